// Round 9
// baseline (226.384 us; speedup 1.0000x reference)
//
#include <hip/hip_runtime.h>
#include <hip/hip_bf16.h>

#define NBATCH 256
#define NT 512
#define ND 256
#define NROWS (NBATCH * NT)
#define CHUNK 128
#define NCHUNK (NROWS / CHUNK)    // 1024 blocks, 4 chunks per batch

typedef __attribute__((ext_vector_type(8))) short short8;
typedef __attribute__((ext_vector_type(4))) float floatx4;

__device__ __forceinline__ unsigned short f2bf(float x) {
    // round-to-nearest-even fp32 -> bf16
    unsigned int u = __float_as_uint(x);
    u += 0x7FFFu + ((u >> 16) & 1u);
    return (unsigned short)(u >> 16);
}

__device__ __forceinline__ short8 cvt8(float4 lo, float4 hi) {
    short8 v;
    v[0] = (short)f2bf(lo.x); v[1] = (short)f2bf(lo.y);
    v[2] = (short)f2bf(lo.z); v[3] = (short)f2bf(lo.w);
    v[4] = (short)f2bf(hi.x); v[5] = (short)f2bf(hi.y);
    v[6] = (short)f2bf(hi.z); v[7] = (short)f2bf(hi.w);
    return v;
}

// prep: W fp32 [D,D] (e,d) -> bf16 chunks in MFMA-FRAG ORDER.
// chunk g (16B = 8 bf16) = nb*512 + s*64 + q*16 + m
//   <-> W[e = nb*16 + m][k = q*8 + s*32 .. +8]
__global__ void __launch_bounds__(256) prep_kernel(
    const float* __restrict__ W, unsigned short* __restrict__ wf)
{
    int g  = blockIdx.x * 256 + threadIdx.x;   // 8192 chunks
    int m  = g & 15, q = (g >> 4) & 3, s = (g >> 6) & 7, nb = g >> 9;
    const float* src = W + (nb * 16 + m) * ND + q * 8 + s * 32;
    float4 f0 = *(const float4*)src;
    float4 f1 = *(const float4*)(src + 4);
    *(short8*)(wf + (long)g * 8) = cvt8(f0, f1);
}

// FUSED v7: convoy-breaking + 2 row-tiles/wave.
// r8 post-mortem: pipes (HBM-A, L2-W, LDS, VALU, MFMA) sum SERIALLY to the
// measured 78us because (a) same-code blocks barrier at the same cadence ->
// CU-wide phase convoys; (b) each wave's W LDS-read is 128KB (512KB/block).
// Fixes: (1) per-block STAGGERED e-loop start (score sum is commutative over
// nb) -> resident blocks work different stages, pipes decorrelate;
// (2) 32 rows/wave (CHUNK=128): each W frag feeds 2 MFMAs -> W LDS + L2
// traffic halves, acc0/acc1 give 2 independent MFMA chains. No waves hint
// (r5's spill came from the (256,4) 64-reg cap; ~110 live fits 128/4-wave).
__global__ void __launch_bounds__(256) fused_kernel(
    const float* __restrict__ ip,             // [B*T, D] fp32
    const unsigned short* __restrict__ wf,    // frag-ordered W bf16
    const float* __restrict__ bias,           // [D] fp32
    const float* __restrict__ ctx,            // [D] fp32
    float* __restrict__ gpart,                // [NCHUNK, 256] fp32 partials
    float2* __restrict__ ml)                  // [NCHUNK] (max, sumexp)
{
    __shared__ __align__(16) short8 wbuf[2][512];    // 2 x 8KB W stage dbuf
    __shared__ float score_s[CHUNK];
    __shared__ float w_s[CHUNK];
    __shared__ __align__(16) float partial[4][ND];

    const int tid  = threadIdx.x;
    const int lane = tid & 63;
    const int wv   = tid >> 6;        // wave 0..3
    const int m    = lane & 15;       // A row / W e-col within tile
    const int q    = lane >> 4;       // k-quad
    const long row0 = (long)blockIdx.x * CHUNK + wv * 32;   // wave's 32 rows
    const int start = blockIdx.x & 15;                      // stagger phase

    const short8* wch = (const short8*)wf;

    // ---- stage-`start` W loads issued first (longest latency cover) ----
    short8 st0 = wch[start * 512 + tid];
    short8 st1 = wch[start * 512 + 256 + tid];

    // ---- A fragments: TWO tiles (32 rows) ----
    short8 a0[8], a1[8];
    {
        const float* ar = ip + (row0 + m) * ND + q * 8;
        float4 raw[8];
#pragma unroll
        for (int g = 0; g < 2; ++g) {
#pragma unroll
            for (int i = 0; i < 4; ++i) {
                raw[2 * i]     = *(const float4*)(ar + (4 * g + i) * 32);
                raw[2 * i + 1] = *(const float4*)(ar + (4 * g + i) * 32 + 4);
            }
#pragma unroll
            for (int i = 0; i < 4; ++i)
                a0[4 * g + i] = cvt8(raw[2 * i], raw[2 * i + 1]);
        }
        const float* br = ar + 16 * ND;   // tile1: rows +16
#pragma unroll
        for (int g = 0; g < 2; ++g) {
#pragma unroll
            for (int i = 0; i < 4; ++i) {
                raw[2 * i]     = *(const float4*)(br + (4 * g + i) * 32);
                raw[2 * i + 1] = *(const float4*)(br + (4 * g + i) * 32 + 4);
            }
#pragma unroll
            for (int i = 0; i < 4; ++i)
                a1[4 * g + i] = cvt8(raw[2 * i], raw[2 * i + 1]);
        }
    }

    // stage-`start` into buf 0
    wbuf[0][tid]       = st0;
    wbuf[0][256 + tid] = st1;
    __syncthreads();

    float sc0[4] = {0.f, 0.f, 0.f, 0.f};
    float sc1[4] = {0.f, 0.f, 0.f, 0.f};
    int cur = 0;

#pragma unroll 1
    for (int i = 0; i < 16; ++i) {
        const int nb = (start + i) & 15;      // rotated stage schedule

        // ---- issue next stage's global loads (consumed after compute) ----
        short8 n0, n1;
        if (i < 15) {
            const int nx = (start + i + 1) & 15;
            n0 = wch[nx * 512 + tid];
            n1 = wch[nx * 512 + 256 + tid];
        }

        // ---- compute e-tile nb from resident buffer: w-frag feeds 2 MFMAs ----
        const short8* wp = &wbuf[cur][0] + lane;   // lane-linear ds_read_b128
        short8 w[4];
#pragma unroll
        for (int s = 0; s < 4; ++s) w[s] = wp[s * 64];
        floatx4 acc0 = {0.f, 0.f, 0.f, 0.f};
        floatx4 acc1 = {0.f, 0.f, 0.f, 0.f};
#pragma unroll
        for (int s = 0; s < 4; ++s) {
            acc0 = __builtin_amdgcn_mfma_f32_16x16x32_bf16(a0[s], w[s], acc0, 0, 0, 0);
            acc1 = __builtin_amdgcn_mfma_f32_16x16x32_bf16(a1[s], w[s], acc1, 0, 0, 0);
        }
#pragma unroll
        for (int s = 0; s < 4; ++s) w[s] = wp[(s + 4) * 64];
#pragma unroll
        for (int s = 0; s < 4; ++s) {
            acc0 = __builtin_amdgcn_mfma_f32_16x16x32_bf16(a0[s + 4], w[s], acc0, 0, 0, 0);
            acc1 = __builtin_amdgcn_mfma_f32_16x16x32_bf16(a1[s + 4], w[s], acc1, 0, 0, 0);
        }

        const int e = nb * 16 + m;
        const float be  = bias[e];        // 1KB tables, L1-hot
        const float ce  = ctx[e];
        const float ce2 = ce + ce;
#pragma unroll
        for (int r = 0; r < 4; ++r) {     // acc[r] = D[row=q*4+r][col=m]
            float x0 = acc0[r] + be;
            float t0 = __builtin_amdgcn_rcpf(__expf(x0 + x0) + 1.f);
            sc0[r] = __builtin_fmaf(-ce2, t0, sc0[r] + ce);
            float x1 = acc1[r] + be;
            float t1 = __builtin_amdgcn_rcpf(__expf(x1 + x1) + 1.f);
            sc1[r] = __builtin_fmaf(-ce2, t1, sc1[r] + ce);
        }

        // ---- write next stage (vmcnt wait for n0/n1 lands here) ----
        if (i < 15) {
            wbuf[cur ^ 1][tid]       = n0;
            wbuf[cur ^ 1][256 + tid] = n1;
        }
        __syncthreads();
        cur ^= 1;
    }

    // sum over 16 e-cols spread across lanes sharing a quad (xor lane bits 0..3)
#pragma unroll
    for (int off = 8; off >= 1; off >>= 1) {
#pragma unroll
        for (int r = 0; r < 4; ++r) {
            sc0[r] += __shfl_xor(sc0[r], off, 64);
            sc1[r] += __shfl_xor(sc1[r], off, 64);
        }
    }
    if (m == 0) {
#pragma unroll
        for (int r = 0; r < 4; ++r) {
            score_s[wv * 32 + q * 4 + r]      = sc0[r];
            score_s[wv * 32 + 16 + q * 4 + r] = sc1[r];
        }
    }
    __syncthreads();

    // ---- chunk softmax over 128 scores (each wave redundantly) ----
    float s0 = score_s[lane], s1 = score_s[64 + lane];
    float mx = fmaxf(s0, s1);
#pragma unroll
    for (int off = 32; off >= 1; off >>= 1) mx = fmaxf(mx, __shfl_xor(mx, off, 64));
    float e0v = __expf(s0 - mx), e1v = __expf(s1 - mx);
    float ls = e0v + e1v;
#pragma unroll
    for (int off = 32; off >= 1; off >>= 1) ls += __shfl_xor(ls, off, 64);
    if (wv == 0) { w_s[lane] = e0v; w_s[64 + lane] = e1v; }   // UNNORMALIZED
    if (tid == 0) ml[blockIdx.x] = make_float2(mx, ls);
    __syncthreads();

    // ---- phase 2: weighted sum, wave wv -> chunk rows [wv*32, wv*32+32) ----
    // lane = float4 col; 1KB contiguous per row across the wave (L2/L3-hot)
    const float4* base = (const float4*)(ip + row0 * ND) + lane;
    float4 acc4 = {0.f, 0.f, 0.f, 0.f};
#pragma unroll 8
    for (int r = 0; r < 32; ++r) {
        const float wt = w_s[wv * 32 + r];    // wave-uniform LDS broadcast
        const float4 v = base[(long)r * 64];
        acc4.x += wt * v.x; acc4.y += wt * v.y;
        acc4.z += wt * v.z; acc4.w += wt * v.w;
    }
    ((float4*)&partial[wv][0])[lane] = acc4;
    __syncthreads();
    {   // 256 threads == ND columns
        float r = partial[0][tid] + partial[1][tid]
                + partial[2][tid] + partial[3][tid];
        gpart[(long)blockIdx.x * ND + tid] = r;
    }
}

// combine: merge the 4 chunk partials of each batch with softmax rescale.
// out[b,d] = sum_c e^{m_c-M} acc_c[d] / sum_c e^{m_c-M} l_c
__global__ void __launch_bounds__(256) combine_kernel(
    const float4* __restrict__ gpart4,   // [NCHUNK, 64] float4
    const float2* __restrict__ ml,       // [NCHUNK]
    float4* __restrict__ out4)           // [B, 64] float4
{
    const int b = blockIdx.x * 4 + (threadIdx.x >> 6);   // wave -> batch
    const int c = threadIdx.x & 63;
    const float2* mlb = ml + b * 4;
    float mk[4], lk[4];
#pragma unroll
    for (int k = 0; k < 4; ++k) { float2 p = mlb[k]; mk[k] = p.x; lk[k] = p.y; }
    float M = fmaxf(fmaxf(mk[0], mk[1]), fmaxf(mk[2], mk[3]));
    float L = 0.f, f[4];
#pragma unroll
    for (int k = 0; k < 4; ++k) { f[k] = __expf(mk[k] - M); L += f[k] * lk[k]; }
    float4 acc = {0.f, 0.f, 0.f, 0.f};
#pragma unroll
    for (int k = 0; k < 4; ++k) {
        float4 v = gpart4[(long)(b * 4 + k) * 64 + c];
        acc.x += f[k] * v.x; acc.y += f[k] * v.y;
        acc.z += f[k] * v.z; acc.w += f[k] * v.w;
    }
    float inv = 1.f / L;
    acc.x *= inv; acc.y *= inv; acc.z *= inv; acc.w *= inv;
    out4[(long)b * 64 + c] = acc;
}

extern "C" void kernel_launch(void* const* d_in, const int* in_sizes, int n_in,
                              void* d_out, int out_size, void* d_ws, size_t ws_size,
                              hipStream_t stream) {
    const float* ip   = (const float*)d_in[0];
    const float* W    = (const float*)d_in[1];
    const float* bias = (const float*)d_in[2];
    const float* ctx  = (const float*)d_in[3];

    unsigned short* wf = (unsigned short*)d_ws;                              // 128 KB
    float* gpart = (float*)((char*)d_ws + ND * ND * sizeof(unsigned short)); // 1 MB
    float2* ml   = (float2*)((char*)gpart + (long)NCHUNK * ND * sizeof(float)); // 8 KB

    prep_kernel<<<32, 256, 0, stream>>>(W, wf);
    fused_kernel<<<NCHUNK, 256, 0, stream>>>(ip, wf, bias, ctx, gpart, ml);
    combine_kernel<<<NBATCH / 4, 256, 0, stream>>>((const float4*)gpart, ml, (float4*)d_out);
}

// Round 10
// 223.649 us; speedup vs baseline: 1.0122x; 1.0122x over previous
//
#include <hip/hip_runtime.h>
#include <hip/hip_bf16.h>

#define NBATCH 256
#define NT 512
#define ND 256
#define NROWS (NBATCH * NT)
#define CHUNK 64
#define NCHUNK (NROWS / CHUNK)    // 2048 blocks, 8 chunks per batch

typedef __attribute__((ext_vector_type(8))) short short8;
typedef __attribute__((ext_vector_type(4))) float floatx4;

__device__ __forceinline__ unsigned short f2bf(float x) {
    // round-to-nearest-even fp32 -> bf16
    unsigned int u = __float_as_uint(x);
    u += 0x7FFFu + ((u >> 16) & 1u);
    return (unsigned short)(u >> 16);
}

__device__ __forceinline__ short8 cvt8(float4 lo, float4 hi) {
    short8 v;
    v[0] = (short)f2bf(lo.x); v[1] = (short)f2bf(lo.y);
    v[2] = (short)f2bf(lo.z); v[3] = (short)f2bf(lo.w);
    v[4] = (short)f2bf(hi.x); v[5] = (short)f2bf(hi.y);
    v[6] = (short)f2bf(hi.z); v[7] = (short)f2bf(hi.w);
    return v;
}

// prep: W fp32 [D,D] (e,d) -> bf16 chunks in MFMA-FRAG ORDER.
// chunk g (16B = 8 bf16) = nb*512 + s*64 + q*16 + m
//   <-> W[e = nb*16 + m][k = q*8 + s*32 .. +8]
__global__ void __launch_bounds__(256) prep_kernel(
    const float* __restrict__ W, unsigned short* __restrict__ wf)
{
    int g  = blockIdx.x * 256 + threadIdx.x;   // 8192 chunks
    int m  = g & 15, q = (g >> 4) & 3, s = (g >> 6) & 7, nb = g >> 9;
    const float* src = W + (nb * 16 + m) * ND + q * 8 + s * 32;
    float4 f0 = *(const float4*)src;
    float4 f1 = *(const float4*)(src + 4);
    *(short8*)(wf + (long)g * 8) = cvt8(f0, f1);
}

// FUSED v8: HALVED per-wave chain via (row-group x e-half) wave rectangles.
// r4/r8/r9 replay dispatches with ~zero HBM traffic ran at IDENTICAL dur ->
// the limiter is the per-wave serial chain (16 e-tiles of load->MFMA->tanh),
// not bandwidth. The e-sum in scores = sum_e tanh(h)*ctx[e] splits over e:
// wave (wr,eh) computes 32 rows x 128 e = 8 nb-iters (chain/2), each W-frag
// feeding 2 MFMAs (a0/a1, r9-validated regs). W direct from global (L2-hot)
// with one-group-ahead prefetch, no main-loop barriers. Score halves merge
// through 0.5KB LDS. Softmax/phase-2/combine = r8 machinery unchanged.
__global__ void __launch_bounds__(256) fused_kernel(
    const float* __restrict__ ip,             // [B*T, D] fp32
    const unsigned short* __restrict__ wf,    // frag-ordered W bf16
    const float* __restrict__ bias,           // [D] fp32
    const float* __restrict__ ctx,            // [D] fp32
    float* __restrict__ gpart,                // [NCHUNK, 256] fp32 partials
    float2* __restrict__ ml)                  // [NCHUNK] (max, sumexp)
{
    __shared__ float score_p[2][CHUNK];       // [e-half][row]
    __shared__ float w_s[CHUNK];
    __shared__ __align__(16) float partial[4][ND];

    const int tid  = threadIdx.x;
    const int lane = tid & 63;
    const int wv   = tid >> 6;        // wave 0..3
    const int wr   = wv >> 1;         // row-group 0/1 (rows wr*32..+32)
    const int eh   = wv & 1;          // e-half 0/1   (e eh*128..+128)
    const int m    = lane & 15;       // A row / W e-col within tile
    const int q    = lane >> 4;       // k-quad
    const long row0 = (long)blockIdx.x * CHUNK + wr * 32;
    const int start = blockIdx.x & 7;               // stagger phase

    const short8* wch = (const short8*)wf;

    // ---- A fragments: TWO tiles (32 rows) ----
    short8 a0[8], a1[8];
    {
        const float* ar = ip + (row0 + m) * ND + q * 8;
        float4 raw[8];
#pragma unroll
        for (int g = 0; g < 2; ++g) {
#pragma unroll
            for (int i = 0; i < 4; ++i) {
                raw[2 * i]     = *(const float4*)(ar + (4 * g + i) * 32);
                raw[2 * i + 1] = *(const float4*)(ar + (4 * g + i) * 32 + 4);
            }
#pragma unroll
            for (int i = 0; i < 4; ++i)
                a0[4 * g + i] = cvt8(raw[2 * i], raw[2 * i + 1]);
        }
        const float* br = ar + 16 * ND;   // tile1: rows +16
#pragma unroll
        for (int g = 0; g < 2; ++g) {
#pragma unroll
            for (int i = 0; i < 4; ++i) {
                raw[2 * i]     = *(const float4*)(br + (4 * g + i) * 32);
                raw[2 * i + 1] = *(const float4*)(br + (4 * g + i) * 32 + 4);
            }
#pragma unroll
            for (int i = 0; i < 4; ++i)
                a1[4 * g + i] = cvt8(raw[2 * i], raw[2 * i + 1]);
        }
    }

    float sc0[4] = {0.f, 0.f, 0.f, 0.f};
    float sc1[4] = {0.f, 0.f, 0.f, 0.f};

    // ---- 8 e-tiles (this wave's half), W prefetched one group ahead ----
    short8 w0[4], w1[4];
#pragma unroll
    for (int s = 0; s < 4; ++s)
        w0[s] = (wch + (eh * 8 + start) * 512 + lane)[s * 64];

#pragma unroll 1
    for (int i = 0; i < 8; ++i) {
        const int t = (start + i) & 7;              // rotated local tile
        const short8* wp = wch + (eh * 8 + t) * 512 + lane;
#pragma unroll
        for (int s = 0; s < 4; ++s) w1[s] = wp[(s + 4) * 64];
        const int e = (eh * 8 + t) * 16 + m;
        const float be = bias[e];         // 1KB tables, L1-hot
        const float ce = ctx[e];

        floatx4 acc0 = {0.f, 0.f, 0.f, 0.f};
        floatx4 acc1 = {0.f, 0.f, 0.f, 0.f};
#pragma unroll
        for (int s = 0; s < 4; ++s) {
            acc0 = __builtin_amdgcn_mfma_f32_16x16x32_bf16(a0[s], w0[s], acc0, 0, 0, 0);
            acc1 = __builtin_amdgcn_mfma_f32_16x16x32_bf16(a1[s], w0[s], acc1, 0, 0, 0);
        }
        if (i < 7) {                      // prefetch next group under MFMAs
            const int tn = (start + i + 1) & 7;
            const short8* wn = wch + (eh * 8 + tn) * 512 + lane;
#pragma unroll
            for (int s = 0; s < 4; ++s) w0[s] = wn[s * 64];
        }
#pragma unroll
        for (int s = 0; s < 4; ++s) {
            acc0 = __builtin_amdgcn_mfma_f32_16x16x32_bf16(a0[s + 4], w1[s], acc0, 0, 0, 0);
            acc1 = __builtin_amdgcn_mfma_f32_16x16x32_bf16(a1[s + 4], w1[s], acc1, 0, 0, 0);
        }

        const float ce2 = ce + ce;
#pragma unroll
        for (int r = 0; r < 4; ++r) {     // acc[r] = D[row=q*4+r][col=m]
            float x0 = acc0[r] + be;
            float t0 = __builtin_amdgcn_rcpf(__expf(x0 + x0) + 1.f);
            sc0[r] = __builtin_fmaf(-ce2, t0, sc0[r] + ce);
            float x1 = acc1[r] + be;
            float t1 = __builtin_amdgcn_rcpf(__expf(x1 + x1) + 1.f);
            sc1[r] = __builtin_fmaf(-ce2, t1, sc1[r] + ce);
        }
    }

    // sum over 16 e-cols spread across lanes sharing a quad (xor lane bits 0..3)
#pragma unroll
    for (int off = 8; off >= 1; off >>= 1) {
#pragma unroll
        for (int r = 0; r < 4; ++r) {
            sc0[r] += __shfl_xor(sc0[r], off, 64);
            sc1[r] += __shfl_xor(sc1[r], off, 64);
        }
    }
    if (m == 0) {
#pragma unroll
        for (int r = 0; r < 4; ++r) {
            score_p[eh][wr * 32 + q * 4 + r]      = sc0[r];
            score_p[eh][wr * 32 + 16 + q * 4 + r] = sc1[r];
        }
    }
    __syncthreads();

    // ---- chunk softmax over 64 rows: merge e-halves, each wave redundant ----
    float s0 = score_p[0][lane] + score_p[1][lane];
    float mx = s0;
#pragma unroll
    for (int off = 32; off >= 1; off >>= 1) mx = fmaxf(mx, __shfl_xor(mx, off, 64));
    float ev = __expf(s0 - mx);
    float ls = ev;
#pragma unroll
    for (int off = 32; off >= 1; off >>= 1) ls += __shfl_xor(ls, off, 64);
    if (wv == 0) w_s[lane] = ev;                  // UNNORMALIZED e^{s-mx}
    if (tid == 0) ml[blockIdx.x] = make_float2(mx, ls);
    __syncthreads();

    // ---- phase 2: weighted sum, wave wv -> chunk rows [wv*16, wv*16+16) ----
    // lane = float4 col; 1KB contiguous per row across the wave (L2/L3-hot)
    const int prow = wv * 16;
    const float4* base = (const float4*)(ip + ((long)blockIdx.x * CHUNK + prow) * ND) + lane;
    float4 acc4 = {0.f, 0.f, 0.f, 0.f};
#pragma unroll
    for (int r = 0; r < 16; ++r) {
        const float wt = w_s[prow + r];   // wave-uniform LDS broadcast
        const float4 v = base[(long)r * 64];
        acc4.x += wt * v.x; acc4.y += wt * v.y;
        acc4.z += wt * v.z; acc4.w += wt * v.w;
    }
    ((float4*)&partial[wv][0])[lane] = acc4;
    __syncthreads();
    {   // 256 threads == ND columns
        float r = partial[0][tid] + partial[1][tid]
                + partial[2][tid] + partial[3][tid];
        gpart[(long)blockIdx.x * ND + tid] = r;
    }
}

// combine: merge the 8 chunk partials of each batch with softmax rescale.
// out[b,d] = sum_c e^{m_c-M} acc_c[d] / sum_c e^{m_c-M} l_c
__global__ void __launch_bounds__(256) combine_kernel(
    const float4* __restrict__ gpart4,   // [NCHUNK, 64] float4
    const float2* __restrict__ ml,       // [NCHUNK]
    float4* __restrict__ out4)           // [B, 64] float4
{
    const int b = blockIdx.x * 4 + (threadIdx.x >> 6);   // wave -> batch
    const int c = threadIdx.x & 63;
    const float2* mlb = ml + b * 8;
    float mk[8], lk[8];
#pragma unroll
    for (int k = 0; k < 8; ++k) { float2 p = mlb[k]; mk[k] = p.x; lk[k] = p.y; }
    float M = mk[0];
#pragma unroll
    for (int k = 1; k < 8; ++k) M = fmaxf(M, mk[k]);
    float L = 0.f, f[8];
#pragma unroll
    for (int k = 0; k < 8; ++k) { f[k] = __expf(mk[k] - M); L += f[k] * lk[k]; }
    float4 acc = {0.f, 0.f, 0.f, 0.f};
#pragma unroll
    for (int k = 0; k < 8; ++k) {
        float4 v = gpart4[(long)(b * 8 + k) * 64 + c];
        acc.x += f[k] * v.x; acc.y += f[k] * v.y;
        acc.z += f[k] * v.z; acc.w += f[k] * v.w;
    }
    float inv = 1.f / L;
    acc.x *= inv; acc.y *= inv; acc.z *= inv; acc.w *= inv;
    out4[(long)b * 64 + c] = acc;
}

extern "C" void kernel_launch(void* const* d_in, const int* in_sizes, int n_in,
                              void* d_out, int out_size, void* d_ws, size_t ws_size,
                              hipStream_t stream) {
    const float* ip   = (const float*)d_in[0];
    const float* W    = (const float*)d_in[1];
    const float* bias = (const float*)d_in[2];
    const float* ctx  = (const float*)d_in[3];

    unsigned short* wf = (unsigned short*)d_ws;                              // 128 KB
    float* gpart = (float*)((char*)d_ws + ND * ND * sizeof(unsigned short)); // 2 MB
    float2* ml   = (float2*)((char*)gpart + (long)NCHUNK * ND * sizeof(float)); // 16 KB

    prep_kernel<<<32, 256, 0, stream>>>(W, wf);
    fused_kernel<<<NCHUNK, 256, 0, stream>>>(ip, wf, bias, ctx, gpart, ml);
    combine_kernel<<<NBATCH / 4, 256, 0, stream>>>((const float4*)gpart, ml, (float4*)d_out);
}